// Round 4
// baseline (132.231 us; speedup 1.0000x reference)
//
#include <hip/hip_runtime.h>
#include <math.h>

#define FEAS 4096
#define K 64
#define BATCH 4096
#define NCROSS 64                 // producer blocks
#define GEMV_BLOCKS (BATCH / 4)   // 4 rows (waves) per consumer block
#define MAGIC 0x5ca1ab1eu         // != 0xAAAAAAAA poison

typedef float f4 __attribute__((ext_vector_type(4)));

// ws float layout (no memset needed — every slot read is written first):
//   [p*68 + j] j<64 : partial column sums of V rows [p*64, p*64+64)
//   [p*68 + 64]     : partial sum of squares
//   uint flags[64] at float index NCROSS*68: MAGIC when block p published.

__global__ __launch_bounds__(256, 5) void fused_kernel(
    const float* __restrict__ x, const float* __restrict__ w,
    const float* __restrict__ bias, const float* __restrict__ cross,
    float* __restrict__ ws, float* __restrict__ out) {
    const int tid  = threadIdx.x;
    const int lane = tid & 63;
    unsigned int* const flags = (unsigned int*)(ws + NCROSS * 68);

    if (blockIdx.x < NCROSS) {
        // ---------- producer: cross-matrix partial reduction ----------
        const int rlane = tid >> 6;
        const int row0  = blockIdx.x * 64;
        float s = 0.f, q = 0.f;
#pragma unroll
        for (int i = 0; i < 16; ++i) {
            const int r = row0 + rlane + i * 4;
            const float v = cross[r * K + lane];
            s += v;
            q += v * v;
        }
        __shared__ float ls[256];
        __shared__ float lq[256];
        ls[tid] = s;
        lq[tid] = q;
        __syncthreads();
        if (tid < 64) {  // wave 0
            const float cs = ls[lane] + ls[lane + 64] + ls[lane + 128] + ls[lane + 192];
            ws[blockIdx.x * 68 + lane] = cs;
            float cq = lq[lane] + lq[lane + 64] + lq[lane + 128] + lq[lane + 192];
#pragma unroll
            for (int off = 32; off; off >>= 1) cq += __shfl_down(cq, off, 64);
            if (lane == 0) ws[blockIdx.x * 68 + 64] = cq;
        }
        __syncthreads();   // barrier drains vmcnt: partial stores reached L2
        if (tid == 0) {
            __threadfence();  // agent-scope fence: L2 writeback (cross-XCD)
            __hip_atomic_store(&flags[blockIdx.x], MAGIC,
                               __ATOMIC_RELEASE, __HIP_MEMORY_SCOPE_AGENT);
        }
        return;
    }

    // ---------- consumer: one wave per output row ----------
    const int row = (blockIdx.x - NCROSS) * 4 + (tid >> 6);
    const f4* __restrict__ xr = (const f4*)(x + (size_t)row * FEAS);
    const f4* __restrict__ wv = (const f4*)w;

    float a0 = 0.f, a1 = 0.f, a2 = 0.f, a3 = 0.f;
#pragma unroll
    for (int i = 0; i < 16; ++i) {
        const f4 a = xr[i * 64 + lane];  // coalesced, 1 KiB/wave-instr
        const f4 b = wv[i * 64 + lane];  // 16 KiB, L1/L2-resident
        a0 = fmaf(a.x, b.x, a0);
        a1 = fmaf(a.y, b.y, a1);
        a2 = fmaf(a.z, b.z, a2);
        a3 = fmaf(a.w, b.w, a3);
    }
    float acc = (a0 + a1) + (a2 + a3);
#pragma unroll
    for (int m = 32; m; m >>= 1) acc += __shfl_xor(acc, m, 64);

    // Wait for all 64 producers (they run ~2 us; the dot above took ~10 us,
    // so this almost never iterates). Lane p watches flag p; the wave
    // re-converges when every lane's flag is set.
    while (__hip_atomic_load(&flags[lane], __ATOMIC_ACQUIRE,
                             __HIP_MEMORY_SCOPE_AGENT) != MAGIC) {}

    // Reduce partials (L2-hot, ~17 KiB unique). Acquire above orders these.
    float cs = 0.f;
#pragma unroll 8
    for (int p = 0; p < 64; ++p) cs += ws[p * 68 + lane];
    const float qv = ws[lane * 68 + 64];

    // Fused butterfly: sum_j cs_j^2 and sum_p q_p over the same 64 lanes.
    float t = cs * cs + qv;
#pragma unroll
    for (int m = 32; m; m >>= 1) t += __shfl_xor(t, m, 64);

    if (lane == 0) {
        const float y = acc + 0.5f * t + bias[0];
        out[row] = 1.0f / (1.0f + expf(-y));
    }
}

extern "C" void kernel_launch(void* const* d_in, const int* in_sizes, int n_in,
                              void* d_out, int out_size, void* d_ws, size_t ws_size,
                              hipStream_t stream) {
    const float* x     = (const float*)d_in[0];  // (4096, 4096)
    const float* cross = (const float*)d_in[1];  // (4096, 1, 64)
    const float* w     = (const float*)d_in[2];  // (1, 4096)
    const float* b     = (const float*)d_in[3];  // (1,)
    float* out = (float*)d_out;                  // (4096, 1)
    float* ws  = (float*)d_ws;

    // Single dispatch: producers (64 blocks) + consumers (1024 blocks).
    // No memset: flags use MAGIC != poison; partials are write-before-read.
    fused_kernel<<<NCROSS + GEMV_BLOCKS, 256, 0, stream>>>(x, w, b, cross, ws, out);
}

// Round 5
// 99.117 us; speedup vs baseline: 1.3341x; 1.3341x over previous
//
#include <hip/hip_runtime.h>
#include <math.h>

#define FEAS 4096
#define K 64
#define BATCH 4096

typedef float f4 __attribute__((ext_vector_type(4)));

// ws layout (floats): 64 partial blocks, stride 68.
//   ws[p*68 + j]  (j=0..63) = partial column sum of rows [p*64, p*64+64)
//   ws[p*68 + 64]           = partial sum of squares for those rows
// No memset, no atomics: every slot read is written exactly once.
// (R4 lesson: intra-grid agent-scope sync thrashes per-XCD L2s; the kernel
//  boundary IS the cheap producer->consumer sync here.)

__global__ __launch_bounds__(256) void cross_reduce_kernel(
    const float* __restrict__ cross, float* __restrict__ ws) {
    // 64 blocks x 256 threads; block p handles rows [p*64, p*64+64) of V (4096x64)
    const int tid   = threadIdx.x;
    const int j     = tid & 63;   // column 0..63
    const int rlane = tid >> 6;   // 0..3
    const int row0  = blockIdx.x * 64;

    float s = 0.f, q = 0.f;
#pragma unroll
    for (int i = 0; i < 16; ++i) {
        const int r = row0 + rlane + i * 4;
        const float v = cross[r * K + j];
        s += v;
        q += v * v;
    }

    __shared__ float ls[256];
    __shared__ float lq[256];
    ls[tid] = s;
    lq[tid] = q;
    __syncthreads();

    if (tid < 64) {  // wave 0 only
        const float cs = ls[j] + ls[j + 64] + ls[j + 128] + ls[j + 192];
        ws[blockIdx.x * 68 + j] = cs;

        float cq = lq[j] + lq[j + 64] + lq[j + 128] + lq[j + 192];
#pragma unroll
        for (int off = 32; off; off >>= 1) cq += __shfl_down(cq, off, 64);
        if (j == 0) ws[blockIdx.x * 68 + 64] = cq;
    }
}

// Wave-per-row GEMV: no LDS, no __syncthreads.
// Dot-product loads issued FIRST; ws-partial reduction hides under the x stream.
__global__ __launch_bounds__(256) void gemv_sigmoid_kernel(
    const float* __restrict__ x, const float* __restrict__ w,
    const float* __restrict__ bias, const float* __restrict__ ws,
    float* __restrict__ out) {
    const int lane = threadIdx.x & 63;
    const int row  = blockIdx.x * 4 + (threadIdx.x >> 6);  // 1024 blocks * 4 waves

    const f4* __restrict__ xr = (const f4*)(x + (size_t)row * FEAS);
    const f4* __restrict__ wv = (const f4*)w;

    float a0 = 0.f, a1 = 0.f, a2 = 0.f, a3 = 0.f;
#pragma unroll
    for (int i = 0; i < 16; ++i) {
        const f4 a = xr[i * 64 + lane];  // coalesced: 64 lanes * 16 B = 1 KiB/instr
        const f4 b = wv[i * 64 + lane];  // 16 KiB, L1/L2-resident
        a0 = fmaf(a.x, b.x, a0);
        a1 = fmaf(a.y, b.y, a1);
        a2 = fmaf(a.z, b.z, a2);
        a3 = fmaf(a.w, b.w, a3);
    }
    float acc = (a0 + a1) + (a2 + a3);
#pragma unroll
    for (int m = 32; m; m >>= 1) acc += __shfl_xor(acc, m, 64);

    // Partial-block reduction (L2-hot, ~17 KiB unique across the grid).
    // lane j accumulates column-sum j; lane p also grabs partial sumsq p.
    float cs = 0.f;
#pragma unroll 8
    for (int p = 0; p < 64; ++p) cs += ws[p * 68 + lane];
    const float qv = ws[lane * 68 + 64];

    // Fused butterfly: sum_j cs_j^2 and sum_p q_p reduce over the same 64 lanes.
    float t = cs * cs + qv;
#pragma unroll
    for (int m = 32; m; m >>= 1) t += __shfl_xor(t, m, 64);

    if (lane == 0) {
        const float y = acc + 0.5f * t + bias[0];
        out[row] = 1.0f / (1.0f + expf(-y));
    }
}

extern "C" void kernel_launch(void* const* d_in, const int* in_sizes, int n_in,
                              void* d_out, int out_size, void* d_ws, size_t ws_size,
                              hipStream_t stream) {
    const float* x     = (const float*)d_in[0];  // (4096, 4096)
    const float* cross = (const float*)d_in[1];  // (4096, 1, 64)
    const float* w     = (const float*)d_in[2];  // (1, 4096)
    const float* b     = (const float*)d_in[3];  // (1,)
    float* out = (float*)d_out;                  // (4096, 1)
    float* ws  = (float*)d_ws;

    // ws is poisoned each iteration, but every slot we read is written first
    // by cross_reduce_kernel — no memset, no atomics needed.
    cross_reduce_kernel<<<64, 256, 0, stream>>>(cross, ws);
    gemv_sigmoid_kernel<<<BATCH / 4, 256, 0, stream>>>(x, w, b, ws, out);
}